// Round 4
// baseline (3688.300 us; speedup 1.0000x reference)
//
#include <hip/hip_runtime.h>

#define NT    262144
#define SDIM  32
#define NSEG  1024           // parallel speculative segments (1 block = 1 wave)
#define SEG   (NT / NSEG)    // 256 steps per segment
#define WARM  192            // warm-up steps; WARM < SEG => warm windows disjoint
#define EPSV  1e-12f
#define L2E   1.4426950408889634f   // log2(e)
#define LN2   0.6931471805599453f
// compact warm-window copy in d_ws: (NSEG-1)*WARM rows of 32 floats, twice
#define WSROWS ((NSEG - 1) * WARM)
#define WS_NEEDED ((size_t)2 * WSROWS * SDIM * 4)

// ---------------------------------------------------------------------------
// Kernel 1: precompute v-independent gate terms, PRE-SCALED for exp2 sigmoids:
//   glN = -log2e*(X@gate_beta), rlN likewise -> out_z / out_cand regions.
// Additionally (if use_ws) writes a compact race-free copy of the warm-up
// windows [b*SEG-WARM, b*SEG) into d_ws (windows disjoint since WARM < SEG).
// ---------------------------------------------------------------------------
__global__ void precompute_lin(const float* __restrict__ X,
                               const float* __restrict__ gb,
                               const float* __restrict__ rg,
                               float* __restrict__ glN,
                               float* __restrict__ rlN,
                               float* __restrict__ wsgl,   // may be null
                               float* __restrict__ wsrl)
{
    int idx = blockIdx.x * blockDim.x + threadIdx.x;   // = t*32 + i
    int t = idx >> 5, i = idx & 31;
    const float* xr = X + (size_t)t * 32;
    float a = 0.f, b = 0.f;
#pragma unroll
    for (int j = 0; j < 32; ++j) {
        float xv = xr[j];
        a = fmaf(xv, gb[j * 32 + i], a);
        b = fmaf(xv, rg[j * 32 + i], b);
    }
    a *= -L2E;  b *= -L2E;
    glN[idx] = a;
    rlN[idx] = b;
    if (wsgl) {
        int m = t & (SEG - 1);                 // t % SEG
        int bw = (t >> 8) + 1;                 // t/SEG + 1 = owning warm window
        if (m >= SEG - WARM && bw < NSEG) {
            int k = m - (SEG - WARM);
            size_t o = ((size_t)(bw - 1) * WARM + k) * SDIM + i;
            wsgl[o] = a;
            wsrl[o] = b;
        }
    }
}

// full-wave (64) sum via DPP row_shr/bcast chain; total lands in lane 63.
__device__ __forceinline__ float wave_sum64(float x) {
    float s = x;
#define DPP_ADD(ctrl)                                                          \
    {   int t_ = __builtin_amdgcn_update_dpp(0, __builtin_bit_cast(int, s),    \
                                             (ctrl), 0xF, 0xF, true);          \
        s += __builtin_bit_cast(float, t_); }
    DPP_ADD(0x111)  // row_shr:1
    DPP_ADD(0x112)  // row_shr:2
    DPP_ADD(0x114)  // row_shr:4
    DPP_ADD(0x118)  // row_shr:8
    DPP_ADD(0x142)  // row_bcast15
    DPP_ADD(0x143)  // row_bcast31 -> lane63 = full sum
#undef DPP_ADD
    return s;
}

// ---------------------------------------------------------------------------
// Kernel 2: speculative-parallel scan. NSEG independent 1-wave blocks.
// Warm-up reads the ws copy (race-free) when available, else recomputes from X.
// ---------------------------------------------------------------------------
__global__ void __launch_bounds__(64, 1)
scan_kernel(const float* __restrict__ returns,
            const float* __restrict__ gsw,
            const float* __restrict__ rsw,
            const float* __restrict__ W1,     // [64, 35]
            const float* __restrict__ b1,     // [64]
            const float* __restrict__ W2,     // [32, 64]
            const float* __restrict__ b2,     // [32]
            const float* __restrict__ X,      // fallback warm-up only
            const float* __restrict__ gb,
            const float* __restrict__ rg,
            const float* __restrict__ wsgl,   // compact warm windows (or null)
            const float* __restrict__ wsrl,
            float* __restrict__ out_sigma,    // [N]
            float* __restrict__ out_z,        // [N*32]  (pre-filled glN)
            float* __restrict__ out_cand,     // [N*32]  (pre-filled rlN)
            float* __restrict__ out_vfinal)   // [32]
{
    const int lane = threadIdx.x;
    const int i    = lane & 31;
    const int bid  = blockIdx.x;
    const int tstart = bid * SEG;
    const int tend   = tstart + SEG;
    const int ws     = tstart - WARM;          // warm start (bid>0 only)

    __shared__ __align__(16) float smA[64];
    __shared__ __align__(16) float smB[64];

    // ---- static weights, pre-scaled so every transcendental is exp2/log2 ----
    const float gswN = -L2E * gsw[i];
    const float rswN = -L2E * rsw[i];
    float w1r[35];
#pragma unroll
    for (int j = 0; j < 35; ++j) w1r[j] = (2.f * L2E) * W1[lane * 35 + j];
    const float b1l = (2.f * L2E) * b1[lane];
    float w2r[64];
#pragma unroll
    for (int j = 0; j < 64; ++j) w2r[j] = L2E * W2[i * 64 + j];
    const float b2l = L2E * b2[i];

    // ---- initial state (block 0 exact; others: bounded guess, converges) ----
    float r00 = returns[(bid == 0) ? 0 : ws];
    float v = r00 * r00;

    auto STEP = [&](int t, float glN, float rlN, float r, bool dostore) {
        // reset gate first -> smA write as early as possible
        float rs = __builtin_amdgcn_rcpf(
                       1.f + __builtin_amdgcn_exp2f(fmaf(rswN, v, rlN)));
        float rv = rs * v;
        smA[lane] = rv;
        __builtin_amdgcn_wave_barrier();

        float zarg = fmaf(gswN, v, glN);       // z deferred to smB latency

        float h0 = b1l;
        h0 = fmaf(w1r[0], r, h0);
        h0 = fmaf(w1r[1], fabsf(r), h0);
        h0 = fmaf(w1r[2], r * r, h0);
        float h1 = 0.f, h2 = 0.f, h3 = 0.f;
        const float4* rvp = (const float4*)smA;
#pragma unroll
        for (int q = 0; q < 8; ++q) {
            float4 x4 = rvp[q];
            h0 = fmaf(w1r[3 + 4 * q + 0], x4.x, h0);
            h1 = fmaf(w1r[3 + 4 * q + 1], x4.y, h1);
            h2 = fmaf(w1r[3 + 4 * q + 2], x4.z, h2);
            h3 = fmaf(w1r[3 + 4 * q + 3], x4.w, h3);
        }
        float hp_ = (h0 + h1) + (h2 + h3);
        float th = fmaf(-2.f,
                        __builtin_amdgcn_rcpf(__builtin_amdgcn_exp2f(hp_) + 1.f),
                        1.f);
        smB[lane] = th;
        __builtin_amdgcn_wave_barrier();

        float z = __builtin_amdgcn_rcpf(1.f + __builtin_amdgcn_exp2f(zarg));

        float p0 = 0.f, p1 = 0.f, p2 = 0.f, p3 = 0.f;
        float p4 = 0.f, p5 = 0.f, p6 = 0.f, p7 = 0.f;
        const float4* hp = (const float4*)smB;
#pragma unroll
        for (int q = 0; q < 16; q += 2) {
            float4 a4 = hp[q];
            p0 = fmaf(w2r[4 * q + 0], a4.x, p0);
            p1 = fmaf(w2r[4 * q + 1], a4.y, p1);
            p2 = fmaf(w2r[4 * q + 2], a4.z, p2);
            p3 = fmaf(w2r[4 * q + 3], a4.w, p3);
            float4 b4 = hp[q + 1];
            p4 = fmaf(w2r[4 * q + 4], b4.x, p4);
            p5 = fmaf(w2r[4 * q + 5], b4.y, p5);
            p6 = fmaf(w2r[4 * q + 6], b4.z, p6);
            p7 = fmaf(w2r[4 * q + 7], b4.w, p7);
        }
        float rawp = (((p0 + p4) + (p1 + p5)) + ((p2 + p6) + (p3 + p7))) + b2l;
        float e  = __builtin_amdgcn_exp2f(-fabsf(rawp));
        float sp = fmaxf(rawp, 0.f) + __builtin_amdgcn_logf(1.f + e);
        float cand = LN2 * sp;

        float vn = fmaxf(fmaf(z, cand - v, v), EPSV);

        if (dostore) {
            out_z  [(size_t)t * SDIM + i] = z;
            out_cand[(size_t)t * SDIM + i] = cand;
            float s = wave_sum64(vn);
            if (lane == 63) out_sigma[t] = s * (1.f / 64.f);
        }
        v = vn;
    };

    // generic 8-deep-pipelined run over stride-32 gl/rl arrays + returns
    auto RUN = [&](const float* __restrict__ gb_, const float* __restrict__ lb_,
                   const float* __restrict__ rb_, int nsteps, int tbase,
                   bool store) {
        float gq[8], lq[8], rq[8];
#pragma unroll
        for (int k = 0; k < 8; ++k) {
            int tt = (k < nsteps) ? k : (nsteps - 1);
            gq[k] = gb_[(size_t)tt * SDIM + i];
            lq[k] = lb_[(size_t)tt * SDIM + i];
            rq[k] = rb_[tt];
        }
        for (int s = 0; s < nsteps; s += 8) {
            float gn[8], ln[8], rn[8];
#pragma unroll
            for (int k = 0; k < 8; ++k) {       // prefetch 8..15 steps ahead
                int tt = s + 8 + k;
                if (tt > nsteps - 1) tt = nsteps - 1;
                gn[k] = gb_[(size_t)tt * SDIM + i];
                ln[k] = lb_[(size_t)tt * SDIM + i];
                rn[k] = rb_[tt];
            }
#pragma unroll
            for (int k = 0; k < 8; ++k)
                STEP(tbase + s + k, gq[k], lq[k], rq[k], store);
#pragma unroll
            for (int k = 0; k < 8; ++k) { gq[k]=gn[k]; lq[k]=ln[k]; rq[k]=rn[k]; }
        }
    };

    // ---- warm-up ----
    if (bid != 0) {
        if (wsgl) {
            const float* gwb = wsgl + (size_t)(bid - 1) * WARM * SDIM;
            const float* rwb = wsrl + (size_t)(bid - 1) * WARM * SDIM;
            RUN(gwb, rwb, returns + ws, WARM, ws, false);
        } else {
            // fallback: recompute gl/rl from X on the fly (race-free)
            float gbN[32], rgN[32];
#pragma unroll
            for (int j = 0; j < 32; ++j) {
                gbN[j] = -L2E * gb[j * 32 + i];
                rgN[j] = -L2E * rg[j * 32 + i];
            }
            float4 xb[8];
            {
                const float4* xr = (const float4*)(X + (size_t)ws * 32);
#pragma unroll
                for (int q = 0; q < 8; ++q) xb[q] = xr[q];
            }
            float rc = returns[ws];
            for (int t = ws; t < tstart; ++t) {
                int tn = (t + 1 < tstart) ? (t + 1) : t;
                float4 xn[8];
                const float4* xr = (const float4*)(X + (size_t)tn * 32);
#pragma unroll
                for (int q = 0; q < 8; ++q) xn[q] = xr[q];
                float rn_ = returns[tn];
                float a0 = 0.f, a1 = 0.f, a2 = 0.f, a3 = 0.f;
                float c0 = 0.f, c1 = 0.f, c2 = 0.f, c3 = 0.f;
#pragma unroll
                for (int q = 0; q < 8; ++q) {
                    float4 x4 = xb[q];
                    a0 = fmaf(gbN[4 * q + 0], x4.x, a0);
                    a1 = fmaf(gbN[4 * q + 1], x4.y, a1);
                    a2 = fmaf(gbN[4 * q + 2], x4.z, a2);
                    a3 = fmaf(gbN[4 * q + 3], x4.w, a3);
                    c0 = fmaf(rgN[4 * q + 0], x4.x, c0);
                    c1 = fmaf(rgN[4 * q + 1], x4.y, c1);
                    c2 = fmaf(rgN[4 * q + 2], x4.z, c2);
                    c3 = fmaf(rgN[4 * q + 3], x4.w, c3);
                }
                STEP(t, (a0 + a1) + (a2 + a3), (c0 + c1) + (c2 + c3), rc, false);
#pragma unroll
                for (int q = 0; q < 8; ++q) xb[q] = xn[q];
                rc = rn_;
            }
        }
    }

    // ---- owned segment (reads clamped to own range; overwrites in place) ----
    RUN(out_z + (size_t)tstart * SDIM, out_cand + (size_t)tstart * SDIM,
        returns + tstart, SEG, tstart, true);

    if (bid == NSEG - 1 && lane < SDIM) out_vfinal[i] = v;
}

// ---------------------------------------------------------------------------
extern "C" void kernel_launch(void* const* d_in, const int* in_sizes, int n_in,
                              void* d_out, int out_size, void* d_ws, size_t ws_size,
                              hipStream_t stream)
{
    const float* X          = (const float*)d_in[0];
    const float* returns    = (const float*)d_in[1];
    const float* gate_beta  = (const float*)d_in[2];
    const float* gsw        = (const float*)d_in[3];
    const float* reset_gamma= (const float*)d_in[4];
    const float* rsw        = (const float*)d_in[5];
    const float* W1         = (const float*)d_in[6];
    const float* b1         = (const float*)d_in[7];
    const float* W2         = (const float*)d_in[8];
    const float* b2         = (const float*)d_in[9];

    float* out       = (float*)d_out;
    float* out_sigma = out;                                   // [N]
    float* out_z     = out + NT;                              // [N*S]
    float* out_cand  = out + NT + (size_t)NT * SDIM;          // [N*S]
    float* out_vfin  = out + NT + 2 * (size_t)NT * SDIM;      // [S]

    const bool use_ws = (ws_size >= WS_NEEDED);
    float* wsgl = use_ws ? (float*)d_ws : nullptr;
    float* wsrl = use_ws ? ((float*)d_ws + (size_t)WSROWS * SDIM) : nullptr;

    precompute_lin<<<(NT * SDIM) / 256, 256, 0, stream>>>(
        X, gate_beta, reset_gamma, out_z, out_cand, wsgl, wsrl);

    scan_kernel<<<NSEG, 64, 0, stream>>>(
        returns, gsw, rsw, W1, b1, W2, b2,
        X, gate_beta, reset_gamma, wsgl, wsrl,
        out_sigma, out_z, out_cand, out_vfin);
}

// Round 6
// 414.110 us; speedup vs baseline: 8.9066x; 8.9066x over previous
//
#include <hip/hip_runtime.h>

#define NT    262144
#define SDIM  32
#define NSEG  1024           // parallel speculative segments (1 block = 1 wave)
#define SEG   (NT / NSEG)    // 256 steps per segment
#define WARM  192            // warm-up steps; WARM < SEG => warm windows disjoint
#define EPSV  1e-12f
#define L2E   1.4426950408889634f   // log2(e)
#define LN2   0.6931471805599453f
// compact warm-window copy in d_ws: (NSEG-1)*WARM rows of 32 floats, twice
#define WSROWS ((NSEG - 1) * WARM)
#define WS_NEEDED ((size_t)2 * WSROWS * SDIM * 4)

// ---------------------------------------------------------------------------
// Kernel 1: precompute v-independent gate terms, PRE-SCALED for exp2 sigmoids:
//   glN = -log2e*(X@gate_beta), rlN likewise -> out_z / out_cand regions.
// If ws is available, also writes a compact race-free copy of each warm-up
// window [b*SEG-WARM, b*SEG) into d_ws (windows disjoint since WARM < SEG).
// ---------------------------------------------------------------------------
__global__ void precompute_lin(const float* __restrict__ X,
                               const float* __restrict__ gb,
                               const float* __restrict__ rg,
                               float* __restrict__ glN,
                               float* __restrict__ rlN,
                               float* __restrict__ wsgl,   // may be null
                               float* __restrict__ wsrl)
{
    int idx = blockIdx.x * blockDim.x + threadIdx.x;   // = t*32 + i
    int t = idx >> 5, i = idx & 31;
    const float* xr = X + (size_t)t * 32;
    float a = 0.f, b = 0.f;
#pragma unroll
    for (int j = 0; j < 32; ++j) {
        float xv = xr[j];
        a = fmaf(xv, gb[j * 32 + i], a);
        b = fmaf(xv, rg[j * 32 + i], b);
    }
    a *= -L2E;  b *= -L2E;
    glN[idx] = a;
    rlN[idx] = b;
    if (wsgl) {
        int m  = t % SEG;
        int bw = t / SEG + 1;                  // owning warm window
        if (m >= SEG - WARM && bw < NSEG) {
            int k = m - (SEG - WARM);
            size_t o = ((size_t)(bw - 1) * WARM + k) * SDIM + i;
            wsgl[o] = a;
            wsrl[o] = b;
        }
    }
}

// DPP partial-sum add (row_shr / row_bcast chain; total lands in lane 63)
#define DPP_ADD(S_, CTRL_)                                                     \
{   int t__ = __builtin_amdgcn_update_dpp(0, __builtin_bit_cast(int, (S_)),    \
                                          (CTRL_), 0xF, 0xF, true);            \
    (S_) += __builtin_bit_cast(float, t__); }

// ---------------------------------------------------------------------------
// one GRU-cell step; consumes glN_/rlN_ (pre-negated-scaled), r; updates v.
// T_ is evaluated into tIdx_ FIRST, before any local declarations, so macro
// arguments can safely reference enclosing-scope names (hygiene).
// ---------------------------------------------------------------------------
#define STEP(T_, GLN_, RLN_, RR_, DOSTORE_)                                    \
{                                                                              \
    const int tIdx_ = (T_);                                                    \
    float rs_ = __builtin_amdgcn_rcpf(                                         \
                    1.f + __builtin_amdgcn_exp2f(fmaf(rswN, v, (RLN_))));      \
    float rv_ = rs_ * v;                                                       \
    smA[lane] = rv_;                                                           \
    __builtin_amdgcn_wave_barrier();                                           \
    float zarg_ = fmaf(gswN, v, (GLN_));                                       \
    float h0_ = b1l;                                                           \
    h0_ = fmaf(w1r[0], (RR_), h0_);                                            \
    h0_ = fmaf(w1r[1], fabsf((RR_)), h0_);                                     \
    h0_ = fmaf(w1r[2], (RR_) * (RR_), h0_);                                    \
    float h1_ = 0.f, h2_ = 0.f, h3_ = 0.f;                                     \
    const float4* rvp_ = (const float4*)smA;                                   \
    _Pragma("unroll")                                                          \
    for (int q_ = 0; q_ < 8; ++q_) {                                           \
        float4 x4_ = rvp_[q_];                                                 \
        h0_ = fmaf(w1r[3 + 4 * q_ + 0], x4_.x, h0_);                           \
        h1_ = fmaf(w1r[3 + 4 * q_ + 1], x4_.y, h1_);                           \
        h2_ = fmaf(w1r[3 + 4 * q_ + 2], x4_.z, h2_);                           \
        h3_ = fmaf(w1r[3 + 4 * q_ + 3], x4_.w, h3_);                           \
    }                                                                          \
    float hp_ = (h0_ + h1_) + (h2_ + h3_);                                     \
    float th_ = fmaf(-2.f,                                                     \
                     __builtin_amdgcn_rcpf(__builtin_amdgcn_exp2f(hp_) + 1.f), \
                     1.f);                                                     \
    smB[lane] = th_;                                                           \
    __builtin_amdgcn_wave_barrier();                                           \
    float z_ = __builtin_amdgcn_rcpf(1.f + __builtin_amdgcn_exp2f(zarg_));     \
    float p0_ = 0.f, p1_ = 0.f, p2_ = 0.f, p3_ = 0.f;                          \
    float p4_ = 0.f, p5_ = 0.f, p6_ = 0.f, p7_ = 0.f;                          \
    const float4* hq_ = (const float4*)smB;                                    \
    _Pragma("unroll")                                                          \
    for (int q_ = 0; q_ < 16; q_ += 2) {                                       \
        float4 a4_ = hq_[q_];                                                  \
        p0_ = fmaf(w2r[4 * q_ + 0], a4_.x, p0_);                               \
        p1_ = fmaf(w2r[4 * q_ + 1], a4_.y, p1_);                               \
        p2_ = fmaf(w2r[4 * q_ + 2], a4_.z, p2_);                               \
        p3_ = fmaf(w2r[4 * q_ + 3], a4_.w, p3_);                               \
        float4 b4_ = hq_[q_ + 1];                                              \
        p4_ = fmaf(w2r[4 * q_ + 4], b4_.x, p4_);                               \
        p5_ = fmaf(w2r[4 * q_ + 5], b4_.y, p5_);                               \
        p6_ = fmaf(w2r[4 * q_ + 6], b4_.z, p6_);                               \
        p7_ = fmaf(w2r[4 * q_ + 7], b4_.w, p7_);                               \
    }                                                                          \
    float raw_ = (((p0_ + p4_) + (p1_ + p5_)) + ((p2_ + p6_) + (p3_ + p7_)))   \
                 + b2l;                                                        \
    float e_  = __builtin_amdgcn_exp2f(-fabsf(raw_));                          \
    float sp_ = fmaxf(raw_, 0.f) + __builtin_amdgcn_logf(1.f + e_);            \
    float cand_ = LN2 * sp_;                                                   \
    float vn_ = fmaxf(fmaf(z_, cand_ - v, v), EPSV);                           \
    if (DOSTORE_) {                                                            \
        out_z  [(size_t)tIdx_ * SDIM + i] = z_;                                \
        out_cand[(size_t)tIdx_ * SDIM + i] = cand_;                            \
        float sAcc_ = vn_;                                                     \
        DPP_ADD(sAcc_, 0x111) DPP_ADD(sAcc_, 0x112) DPP_ADD(sAcc_, 0x114)      \
        DPP_ADD(sAcc_, 0x118) DPP_ADD(sAcc_, 0x142) DPP_ADD(sAcc_, 0x143)      \
        if (lane == 63) out_sigma[tIdx_] = sAcc_ * (1.f / 64.f);               \
    }                                                                          \
    v = vn_;                                                                   \
}

// 4-deep software-pipelined run over stride-32 gl/rl arrays + returns.
// Slot k is refilled (load for step s+k+4) right before STEP consumes it,
// giving every load ~4 steps of latency cover. All queue indices static.
#define PIPE(GP_, LP_, RP_, NSTEPS_, TBASE_, DOSTORE_)                         \
{                                                                              \
    float gq0_, gq1_, gq2_, gq3_, lq0_, lq1_, lq2_, lq3_,                      \
          rq0_, rq1_, rq2_, rq3_;                                              \
    gq0_ = (GP_)[0 * SDIM + i]; lq0_ = (LP_)[0 * SDIM + i]; rq0_ = (RP_)[0];   \
    gq1_ = (GP_)[1 * SDIM + i]; lq1_ = (LP_)[1 * SDIM + i]; rq1_ = (RP_)[1];   \
    gq2_ = (GP_)[2 * SDIM + i]; lq2_ = (LP_)[2 * SDIM + i]; rq2_ = (RP_)[2];   \
    gq3_ = (GP_)[3 * SDIM + i]; lq3_ = (LP_)[3 * SDIM + i]; rq3_ = (RP_)[3];   \
    for (int s_ = 0; s_ < (NSTEPS_); s_ += 4) {                                \
        int t0_ = s_ + 4; if (t0_ > (NSTEPS_) - 1) t0_ = (NSTEPS_) - 1;        \
        float g_ = gq0_, l_ = lq0_, r_ = rq0_;                                 \
        gq0_ = (GP_)[(size_t)t0_ * SDIM + i];                                  \
        lq0_ = (LP_)[(size_t)t0_ * SDIM + i];                                  \
        rq0_ = (RP_)[t0_];                                                     \
        STEP((TBASE_) + s_ + 0, g_, l_, r_, DOSTORE_)                          \
        int t1_ = s_ + 5; if (t1_ > (NSTEPS_) - 1) t1_ = (NSTEPS_) - 1;        \
        g_ = gq1_; l_ = lq1_; r_ = rq1_;                                       \
        gq1_ = (GP_)[(size_t)t1_ * SDIM + i];                                  \
        lq1_ = (LP_)[(size_t)t1_ * SDIM + i];                                  \
        rq1_ = (RP_)[t1_];                                                     \
        STEP((TBASE_) + s_ + 1, g_, l_, r_, DOSTORE_)                          \
        int t2_ = s_ + 6; if (t2_ > (NSTEPS_) - 1) t2_ = (NSTEPS_) - 1;        \
        g_ = gq2_; l_ = lq2_; r_ = rq2_;                                       \
        gq2_ = (GP_)[(size_t)t2_ * SDIM + i];                                  \
        lq2_ = (LP_)[(size_t)t2_ * SDIM + i];                                  \
        rq2_ = (RP_)[t2_];                                                     \
        STEP((TBASE_) + s_ + 2, g_, l_, r_, DOSTORE_)                          \
        int t3_ = s_ + 7; if (t3_ > (NSTEPS_) - 1) t3_ = (NSTEPS_) - 1;        \
        g_ = gq3_; l_ = lq3_; r_ = rq3_;                                       \
        gq3_ = (GP_)[(size_t)t3_ * SDIM + i];                                  \
        lq3_ = (LP_)[(size_t)t3_ * SDIM + i];                                  \
        rq3_ = (RP_)[t3_];                                                     \
        STEP((TBASE_) + s_ + 3, g_, l_, r_, DOSTORE_)                          \
    }                                                                          \
}

__global__ void __launch_bounds__(64, 1)
scan_kernel(const float* __restrict__ returns,
            const float* __restrict__ gsw,
            const float* __restrict__ rsw,
            const float* __restrict__ W1,     // [64, 35]
            const float* __restrict__ b1,     // [64]
            const float* __restrict__ W2,     // [32, 64]
            const float* __restrict__ b2,     // [32]
            const float* __restrict__ X,      // fallback warm-up only
            const float* __restrict__ gb,
            const float* __restrict__ rg,
            const float* __restrict__ wsgl,   // compact warm windows (or null)
            const float* __restrict__ wsrl,
            float* __restrict__ out_sigma,    // [N]
            float* __restrict__ out_z,        // [N*32]  (pre-filled glN)
            float* __restrict__ out_cand,     // [N*32]  (pre-filled rlN)
            float* __restrict__ out_vfinal)   // [32]
{
    const int lane = threadIdx.x;
    const int i    = lane & 31;
    const int bid  = blockIdx.x;
    const int tstart = bid * SEG;
    const int wst    = tstart - WARM;          // warm start (bid>0 only)

    __shared__ __align__(16) float smA[64];
    __shared__ __align__(16) float smB[64];
    __shared__ __align__(16) float smGB[32 * 32];   // fallback only
    __shared__ __align__(16) float smRG[32 * 32];   // fallback only

    // ---- static weights, pre-scaled so every transcendental is exp2/log2 ----
    const float gswN = -L2E * gsw[i];
    const float rswN = -L2E * rsw[i];
    float w1r[35];
#pragma unroll
    for (int j = 0; j < 35; ++j) w1r[j] = (2.f * L2E) * W1[lane * 35 + j];
    const float b1l = (2.f * L2E) * b1[lane];
    float w2r[64];
#pragma unroll
    for (int j = 0; j < 64; ++j) w2r[j] = L2E * W2[i * 64 + j];
    const float b2l = L2E * b2[i];

    // ---- initial state (block 0 exact; others: bounded guess, converges) ----
    float r00 = returns[(bid == 0) ? 0 : wst];
    float v = r00 * r00;

    // ---- warm-up ----
    if (bid != 0) {
        if (wsgl) {
            const float* gwb = wsgl + (size_t)(bid - 1) * WARM * SDIM;
            const float* rwb = wsrl + (size_t)(bid - 1) * WARM * SDIM;
            const float* rr  = returns + wst;
            PIPE(gwb, rwb, rr, WARM, wst, false)
        } else {
            // cold fallback: stage scaled beta matrices in LDS, recompute gl/rl
            for (int k = lane; k < 1024; k += 64) {
                smGB[k] = -L2E * gb[k];
                smRG[k] = -L2E * rg[k];
            }
            __syncthreads();
            for (int t = wst; t < tstart; ++t) {
                const float* xr = X + (size_t)t * 32;
                float a0 = 0.f, a1 = 0.f, c0 = 0.f, c1 = 0.f;
#pragma unroll
                for (int j = 0; j < 32; j += 2) {
                    float x0 = xr[j], x1 = xr[j + 1];
                    a0 = fmaf(x0, smGB[j * 32 + i], a0);
                    c0 = fmaf(x0, smRG[j * 32 + i], c0);
                    a1 = fmaf(x1, smGB[(j + 1) * 32 + i], a1);
                    c1 = fmaf(x1, smRG[(j + 1) * 32 + i], c1);
                }
                float rc = returns[t];
                STEP(t, a0 + a1, c0 + c1, rc, false)
            }
        }
    }

    // ---- owned segment (reads clamped to own range; overwrites in place) ----
    {
        const float* gsp = out_z   + (size_t)tstart * SDIM;
        const float* lsp = out_cand + (size_t)tstart * SDIM;
        const float* rsp = returns + tstart;
        PIPE(gsp, lsp, rsp, SEG, tstart, true)
    }

    if (bid == NSEG - 1 && lane < SDIM) out_vfinal[i] = v;
}

// ---------------------------------------------------------------------------
extern "C" void kernel_launch(void* const* d_in, const int* in_sizes, int n_in,
                              void* d_out, int out_size, void* d_ws, size_t ws_size,
                              hipStream_t stream)
{
    const float* X          = (const float*)d_in[0];
    const float* returns    = (const float*)d_in[1];
    const float* gate_beta  = (const float*)d_in[2];
    const float* gsw        = (const float*)d_in[3];
    const float* reset_gamma= (const float*)d_in[4];
    const float* rsw        = (const float*)d_in[5];
    const float* W1         = (const float*)d_in[6];
    const float* b1         = (const float*)d_in[7];
    const float* W2         = (const float*)d_in[8];
    const float* b2         = (const float*)d_in[9];

    float* out       = (float*)d_out;
    float* out_sigma = out;                                   // [N]
    float* out_z     = out + NT;                              // [N*S]
    float* out_cand  = out + NT + (size_t)NT * SDIM;          // [N*S]
    float* out_vfin  = out + NT + 2 * (size_t)NT * SDIM;      // [S]

    const bool use_ws = (ws_size >= WS_NEEDED);
    float* wsgl = use_ws ? (float*)d_ws : nullptr;
    float* wsrl = use_ws ? ((float*)d_ws + (size_t)WSROWS * SDIM) : nullptr;

    precompute_lin<<<(NT * SDIM) / 256, 256, 0, stream>>>(
        X, gate_beta, reset_gamma, out_z, out_cand, wsgl, wsrl);

    scan_kernel<<<NSEG, 64, 0, stream>>>(
        returns, gsw, rsw, W1, b1, W2, b2,
        X, gate_beta, reset_gamma, wsgl, wsrl,
        out_sigma, out_z, out_cand, out_vfin);
}